// Round 1
// baseline (1176.870 us; speedup 1.0000x reference)
//
#include <hip/hip_runtime.h>
#include <hip/hip_bf16.h>

#define NB 8192
#define NS 12
#define NH 8
#define NDK 64
#define NDM 512

typedef __attribute__((ext_vector_type(8))) short bf16x8;
typedef __attribute__((ext_vector_type(4))) float f32x4;

__global__ __launch_bounds__(512) void wcvt_kernel(const float* __restrict__ W,
                                                   __hip_bfloat16* __restrict__ Wb) {
    int i = blockIdx.x * 512 + threadIdx.x;
    Wb[i] = __float2bfloat16(W[i]);
}

__global__ __launch_bounds__(512) void mha_fused_kernel(
    const float* __restrict__ gq, const float* __restrict__ gk, const float* __restrict__ gv,
    const int* __restrict__ gmask, const float* __restrict__ gcw, const float* __restrict__ gcb,
    const __hip_bfloat16* __restrict__ Wb, const float* __restrict__ gbo,
    float* __restrict__ gout)
{
    __shared__ float xbuf[NS][NDM];        // 24576 B : staged input tensor
    __shared__ float nsbuf[NH][NS][66];    // 25344 B : neighbor sums (+pad); later overlaid by abuf (bf16 [16][520])
    __shared__ float qc[NH][NS][NDK];      // 24576 B
    __shared__ float kc[NH][NS][NDK];      // 24576 B
    __shared__ float vc[NH][NS][NDK];      // 24576 B
    __shared__ float wconv[NS][NS][3];     // 1728 B
    __shared__ float bconv[NS];            // 48 B
    __shared__ float probs[NH][NS][NS];    // 4608 B
    // total ~130 KB -> 1 block/CU

    const int b = blockIdx.x;
    const int tid = threadIdx.x;

    if (tid < 432) (&wconv[0][0][0])[tid] = gcw[tid];
    if (tid >= 432 && tid < 444) bconv[tid - 432] = gcb[tid - 432];

    const size_t xoff = (size_t)b * (NS * NDM);

    for (int t3 = 0; t3 < 3; ++t3) {
        const float* src = (t3 == 0) ? gq : (t3 == 1) ? gk : gv;
        float* dst = (t3 == 0) ? &qc[0][0][0] : (t3 == 1) ? &kc[0][0][0] : &vc[0][0][0];

        // ---- stage x[12][512] (coalesced float4) ----
        {
            const float4* s4 = (const float4*)(src + xoff);
            float4* x4 = (float4*)&xbuf[0][0];
            #pragma unroll
            for (int i = 0; i < 3; ++i) x4[tid + i * 512] = s4[tid + i * 512];
        }
        __syncthreads();

        // ---- neighbor sums over head axis, with DK zero-pad columns ----
        if (tid < 192) {
            int h = tid / 24, r = tid % 24, s = r >> 1;
            nsbuf[h][s][(r & 1) ? 65 : 0] = 0.0f;
        }
        #pragma unroll
        for (int i = 0; i < 12; ++i) {
            int idx = tid + i * 512;          // 0..6143
            int h = idx / 768;
            int rem = idx - h * 768;
            int s = rem >> 6, d = rem & 63;
            float acc = xbuf[s][h * 64 + d];
            if (h > 0) acc += xbuf[s][(h - 1) * 64 + d];
            if (h < 7) acc += xbuf[s][(h + 1) * 64 + d];
            nsbuf[h][s][1 + d] = acc;
        }
        __syncthreads();

        // ---- conv1d (channels=S, kernel=3, pad=1 along DK). thread=(h,d): wave-uniform h ----
        {
            int h = tid >> 6, d = tid & 63;
            float col[NS][3];
            #pragma unroll
            for (int s2 = 0; s2 < NS; ++s2) {
                #pragma unroll
                for (int t = 0; t < 3; ++t) col[s2][t] = nsbuf[h][s2][d + t];
            }
            #pragma unroll
            for (int s = 0; s < NS; ++s) {
                float acc = bconv[s];
                #pragma unroll
                for (int s2 = 0; s2 < NS; ++s2) {
                    acc += wconv[s][s2][0] * col[s2][0];
                    acc += wconv[s][s2][1] * col[s2][1];
                    acc += wconv[s][s2][2] * col[s2][2];
                }
                dst[(h * NS + s) * NDK + d] = acc;
            }
        }
        __syncthreads();
    }

    // ---- scores = qc . kc / 8, mask, into probs ----
    #pragma unroll
    for (int i = 0; i < 3; ++i) {
        int idx = tid + i * 512;
        if (idx < 1152) {
            int h = idx / 144;
            int r = idx - h * 144;
            int qi = r / 12;
            int kj = r - qi * 12;
            const float4* qp = (const float4*)&qc[h][qi][0];
            const float4* kp = (const float4*)&kc[h][kj][0];
            float dot = 0.f;
            #pragma unroll
            for (int d4 = 0; d4 < 16; ++d4) {
                float4 a = qp[d4], c = kp[d4];
                dot += a.x * c.x + a.y * c.y + a.z * c.z + a.w * c.w;
            }
            float sc = dot * 0.125f;
            if (gmask[(size_t)b * 144 + qi * 12 + kj] == 0) sc = -1e9f;
            probs[h][qi][kj] = sc;
        }
    }
    __syncthreads();

    // ---- softmax per (h, qi) row ----
    if (tid < 96) {
        int h = tid / 12, qi = tid - (tid / 12) * 12;
        float m = -3.4e38f;
        #pragma unroll
        for (int j = 0; j < 12; ++j) m = fmaxf(m, probs[h][qi][j]);
        float e[12]; float sum = 0.f;
        #pragma unroll
        for (int j = 0; j < 12; ++j) { e[j] = __expf(probs[h][qi][j] - m); sum += e[j]; }
        float inv = 1.0f / sum;
        #pragma unroll
        for (int j = 0; j < 12; ++j) probs[h][qi][j] = e[j] * inv;
    }
    __syncthreads();

    // ---- PV -> abuf bf16 [16][520] (overlays nsbuf; rows 12..15 zero) ----
    __hip_bfloat16* abuf = (__hip_bfloat16*)&nsbuf[0][0][0];
    {
        if (tid < 520) {
            #pragma unroll
            for (int r = 12; r < 16; ++r) abuf[r * 520 + tid] = __float2bfloat16(0.f);
        }
        int h = tid >> 6, d = tid & 63;
        #pragma unroll
        for (int qi = 0; qi < NS; ++qi) {
            float acc = 0.f;
            #pragma unroll
            for (int j = 0; j < NS; ++j) acc += probs[h][qi][j] * vc[h][j][d];
            abuf[qi * 520 + h * 64 + d] = __float2bfloat16(acc);
        }
    }
    __syncthreads();

    // ---- projection: out[m][n] = sum_k A[m][k]*W[n][k] + b_out[n], bf16 MFMA 16x16x32 ----
    {
        const short* Ws = (const short*)Wb;
        const short* As = (const short*)abuf;
        const int wv = tid >> 6, lane = tid & 63;
        const int rowA = lane & 15;
        const int kgrp = (lane >> 4) * 8;
        f32x4 acc[4] = {};
        const int n_lane = wv * 64 + (lane & 15);
        #pragma unroll 4
        for (int kk = 0; kk < 16; ++kk) {
            int k0 = kk * 32 + kgrp;
            bf16x8 afrag = *(const bf16x8*)(As + rowA * 520 + k0);
            #pragma unroll
            for (int i = 0; i < 4; ++i) {
                bf16x8 bfrag = *(const bf16x8*)(Ws + (size_t)(n_lane + i * 16) * NDM + k0);
                acc[i] = __builtin_amdgcn_mfma_f32_16x16x32_bf16(afrag, bfrag, acc[i], 0, 0, 0);
            }
        }
        float* outb = gout + (size_t)b * (NS * NDM);
        const int m0 = (lane >> 4) * 4;
        #pragma unroll
        for (int i = 0; i < 4; ++i) {
            int n = wv * 64 + i * 16 + (lane & 15);
            float bias = gbo[n];
            #pragma unroll
            for (int r = 0; r < 4; ++r) {
                int m = m0 + r;
                if (m < NS) outb[m * NDM + n] = acc[i][r] + bias;
            }
        }
    }
}

extern "C" void kernel_launch(void* const* d_in, const int* in_sizes, int n_in,
                              void* d_out, int out_size, void* d_ws, size_t ws_size,
                              hipStream_t stream) {
    const float* q    = (const float*)d_in[0];
    const float* k    = (const float*)d_in[1];
    const float* v    = (const float*)d_in[2];
    const int*   mask = (const int*)d_in[3];
    const float* cw   = (const float*)d_in[4];
    const float* cb   = (const float*)d_in[5];
    const float* W    = (const float*)d_in[6];
    const float* bo   = (const float*)d_in[7];
    __hip_bfloat16* Wb = (__hip_bfloat16*)d_ws;   // 512 KB bf16 copy of W_out

    hipLaunchKernelGGL(wcvt_kernel, dim3(512), dim3(512), 0, stream, W, Wb);
    hipLaunchKernelGGL(mha_fused_kernel, dim3(NB), dim3(512), 0, stream,
                       q, k, v, mask, cw, cb, Wb, bo, (float*)d_out);
}